// Round 11
// baseline (57.220 us; speedup 1.0000x reference)
//
#include <hip/hip_runtime.h>

// CenterNeighAtt on MI355X. E=512, F=256, R=4.
//
// Exact math simplifications (validated R1-R9, absmax ~5e-4 vs 2.3e-3 threshold):
//  * alpha = softmax_j(sum_i scores[i,j]) is uniform 1/E: sum_i attention[i,j,f]==1,
//    so column sums of scores are constant in j. lin_w/lin_b are dead inputs.
//  * No max-subtraction in softmaxes: logits bounded (~20), exp far below f32 overflow.
//
// Structure lessons (measured):
//  * Cross-grid sync in-dispatch toxic (coop ~55us/sync R3; flag barrier ~270us R6);
//    __threadfence per block toxic (R5/R7: 78-85us @13% VALUBusy). Kernel boundaries ONLY.
//  * Per-dispatch gap ~3us (R2/R4/R8 dispatch-count deltas).
//  * Interiors are LATENCY-bound, not issue-bound: floor ~7us/pass, measured 15-18
//    at 4 waves/SIMD; 2->4 blk/CU cut kB 16.5->11 (R4->R7). TLP is the lever.
//  * R10: op_sel on v_pk_*_f32 broke math (absmax 0.129) -> no VOP3P asm.
//  * Rule #20: only tiny, fully-unrolled per-thread arrays.
//
// R11 = R9 minus asm, with 1 row/block (512 blk x 1024 thr = 2 blk/CU = 8 waves/SIMD,
// launch_bounds(1024,8) caps VGPR<=64). In-block 4-team split-reduction, no atomics.

typedef float f2 __attribute__((ext_vector_type(2)));

#define EE 512
#define FF 256
#define RRR 4
#define LOG2E 1.44269504088896340736f

// --- kA: s[i,:] = softmax_j(sum_r adj[r,i,:]); alpha -----------------------
__global__ __launch_bounds__(256) void kA(const float* __restrict__ adj,
                                          float* __restrict__ s,
                                          float* __restrict__ out) {
    const int i = blockIdx.x;
    const int t = threadIdx.x;
    if (i == 0) {   // alpha: softmax of a constant vector = uniform 1/E
        out[EE * FF + t]       = 1.0f / EE;
        out[EE * FF + 256 + t] = 1.0f / EE;
    }
    const float* base = adj + (size_t)i * EE;
    float t0 = 0.f, t1 = 0.f;
#pragma unroll
    for (int r = 0; r < RRR; ++r) {
        t0 += base[(size_t)r * EE * EE + t];
        t1 += base[(size_t)r * EE * EE + t + 256];
    }
    const float e0 = __expf(t0);
    const float e1 = __expf(t1);
    __shared__ float red[256];
    red[t] = e0 + e1;
    __syncthreads();
    for (int off = 128; off > 0; off >>= 1) {
        if (t < off) red[t] += red[t + off];
        __syncthreads();
    }
    const float inv = 1.0f / red[0];
    s[(size_t)i * EE + t]       = e0 * inv;
    s[(size_t)i * EE + t + 256] = e1 * inv;
}

// --- kB: Z[j,f] = sum_i exp2(lrelu(s[i,j]*h[i,f]*h[j,f])*log2e);
//         hg[j,f] = {h[j,f], h[j,f]*rcp(Z)}  (fused operand for kC) ---------
__global__ __launch_bounds__(1024, 8) void kB(const float* __restrict__ h,
                                              const float* __restrict__ s,
                                              f2* __restrict__ hg) {
    const int tid  = threadIdx.x;
    const int f    = tid & 255;
    const int team = tid >> 8;            // 0..3, splits the i-axis
    const int j    = blockIdx.x;          // one j per block
    __shared__ float sl[EE];              // sl[i] = s[i][j]
    __shared__ float ps[4 * FF];
    if (tid < EE) sl[tid] = s[(size_t)tid * EE + j];   // one-time scattered stage
    __syncthreads();
    const float hj = h[(size_t)j * FF + f] * LOG2E;    // log2e folded
    float Z = 0.f;
    const float* hp = h + (size_t)(team * 128) * FF + f;
    const float* sp = sl + team * 128;
#pragma unroll 4
    for (int ii = 0; ii < 128; ++ii) {
        const float q = hp[(size_t)ii * FF] * hj;      // coalesced, L1/L2-resident
        const float y = sp[ii] * q;                    // LDS broadcast read
        Z += __builtin_amdgcn_exp2f(fmaxf(y, 0.2f * y));   // lrelu folded
    }
    ps[team * 256 + f] = Z;
    __syncthreads();
    if (tid < 256) {
        const float Zt = ps[tid] + ps[256 + tid] + ps[512 + tid] + ps[768 + tid];
        const float hv = h[(size_t)j * FF + tid];
        hg[(size_t)j * FF + tid] = (f2){hv, hv * __builtin_amdgcn_rcpf(Zt)};
    }
}

// --- kC: out[i,f] = elu(sum_j g[j,f]*exp2(lrelu(s[i,j]*h[i,f]*h[j,f])*log2e))
__global__ __launch_bounds__(1024, 8) void kC(const float* __restrict__ h,
                                              const float* __restrict__ s,
                                              const f2* __restrict__ hg,
                                              float* __restrict__ out) {
    const int tid  = threadIdx.x;
    const int f    = tid & 255;
    const int team = tid >> 8;            // 0..3, splits the j-axis
    const int i    = blockIdx.x;          // one i per block
    __shared__ float sl[EE];              // sl[j] = s[i][j]
    __shared__ float ps[4 * FF];
    if (tid < EE) sl[tid] = s[(size_t)i * EE + tid];   // coalesced row stage
    __syncthreads();
    const float hi = h[(size_t)i * FF + f] * LOG2E;
    float acc = 0.f;
    const f2* hgp = hg + (size_t)(team * 128) * FF + f;
    const float* sp = sl + team * 128;
#pragma unroll 4
    for (int jj = 0; jj < 128; ++jj) {
        const f2 hgv = hgp[(size_t)jj * FF];           // one dwordx2: {h_jf, g_jf}
        const float q = hgv.x * hi;
        const float y = sp[jj] * q;                    // LDS broadcast read
        acc = fmaf(__builtin_amdgcn_exp2f(fmaxf(y, 0.2f * y)), hgv.y, acc);
    }
    ps[team * 256 + f] = acc;
    __syncthreads();
    if (tid < 256) {
        const float a = ps[tid] + ps[256 + tid] + ps[512 + tid] + ps[768 + tid];
        out[(size_t)i * FF + tid] = (a > 0.f) ? a : (__expf(a) - 1.0f);
    }
}

extern "C" void kernel_launch(void* const* d_in, const int* in_sizes, int n_in,
                              void* d_out, int out_size, void* d_ws, size_t ws_size,
                              hipStream_t stream) {
    const float* h   = (const float*)d_in[0];  // [E,F]
    const float* adj = (const float*)d_in[1];  // [R,E,E]
    // lin_w / lin_b mathematically dead (alpha uniform).

    float* s   = (float*)d_ws;                 // 1 MB
    f2*    hg  = (f2*)(s + (size_t)EE * EE);   // 1 MB {h,g} pairs (total 2 MB)
    float* out = (float*)d_out;

    kA<<<EE, 256, 0, stream>>>(adj, s, out);
    kB<<<EE, 1024, 0, stream>>>(h, s, hg);
    kC<<<EE, 1024, 0, stream>>>(h, s, hg, out);
}

// Round 12
// 44.373 us; speedup vs baseline: 1.2895x; 1.2895x over previous
//
#include <hip/hip_runtime.h>

// CenterNeighAtt on MI355X. E=512, F=256, R=4.
//
// Exact math simplifications (validated R1-R11, absmax ~5e-4 vs 2.3e-3 threshold):
//  * alpha = softmax_j(sum_i scores[i,j]) is uniform 1/E: sum_i attention[i,j,f]==1,
//    so column sums of scores are constant in j. lin_w/lin_b are dead inputs.
//  * No max-subtraction in softmaxes: logits bounded (~20), exp far below f32 overflow.
//
// Structure lessons (measured):
//  * Cross-grid sync / __threadfence in-dispatch: toxic (R3/R5/R6/R7). Kernel
//    boundaries + plain partial stores ONLY.
//  * Interiors are L2-BW-bound: traffic = E^2*F*B/rows_per_block; R11's rpb 2->1
//    doubled traffic and cost +14.9us at ~26 TB/s marginal = L2 ceiling.
//  * Per-dispatch gap ~2-3us. Rule #20: only fully-unrolled per-thread arrays.
//  * R10: op_sel on v_pk_*_f32 broke math -> no VOP3P asm.
//
// R12: rpb=8 with 4-way reduction split (grid 64x4=256 blocks x 1024 thr).
// Each h/hg load serves 8 rows in registers: kC traffic 256->64MB, kB 128->32MB.
// Partials to Zp/Hp via plain stores; epilogues kBe (sum+g) / kCe (sum+ELU).

typedef float f2 __attribute__((ext_vector_type(2)));
typedef float f4 __attribute__((ext_vector_type(4)));

#define EE 512
#define FF 256
#define RRR 4
#define LOG2E 1.44269504088896340736f
#define RPB 8            // rows per block
#define SCH 4            // reduction-split chunks
#define CH  (EE / SCH)   // 128 chunk length
#define TLEN (CH / 4)    // 32 per team

// --- kA: s[i,:] = softmax_j(sum_r adj[r,i,:]); alpha -----------------------
__global__ __launch_bounds__(256) void kA(const float* __restrict__ adj,
                                          float* __restrict__ s,
                                          float* __restrict__ out) {
    const int i = blockIdx.x;
    const int t = threadIdx.x;
    if (i == 0) {   // alpha: softmax of a constant vector = uniform 1/E
        out[EE * FF + t]       = 1.0f / EE;
        out[EE * FF + 256 + t] = 1.0f / EE;
    }
    const float* base = adj + (size_t)i * EE;
    float t0 = 0.f, t1 = 0.f;
#pragma unroll
    for (int r = 0; r < RRR; ++r) {
        t0 += base[(size_t)r * EE * EE + t];
        t1 += base[(size_t)r * EE * EE + t + 256];
    }
    const float e0 = __expf(t0);
    const float e1 = __expf(t1);
    __shared__ float red[256];
    red[t] = e0 + e1;
    __syncthreads();
    for (int off = 128; off > 0; off >>= 1) {
        if (t < off) red[t] += red[t + off];
        __syncthreads();
    }
    const float inv = 1.0f / red[0];
    s[(size_t)i * EE + t]       = e0 * inv;
    s[(size_t)i * EE + t + 256] = e1 * inv;
}

// --- kB: Zp[c][j,f] = sum_{i in chunk c} exp2(lrelu(s*h_if*h_jf)*log2e) ----
// block (jg, c): 8 j-rows, 128-i chunk; 4 teams split the chunk; ps-reduce.
__global__ __launch_bounds__(1024, 2) void kB(const float* __restrict__ h,
                                              const float* __restrict__ s,
                                              float* __restrict__ Zp) {
    const int tid  = threadIdx.x;
    const int f    = tid & 255;
    const int team = tid >> 8;
    const int j0   = blockIdx.x * RPB;
    const int i0   = blockIdx.y * CH;
    __shared__ __align__(16) float sl[CH * RPB];   // [ii][jr]
    __shared__ float ps[4 * RPB * FF];             // [team][r][f] = 32 KB
    sl[tid] = s[(size_t)(i0 + (tid >> 3)) * EE + j0 + (tid & 7)];
    __syncthreads();
    float hj[RPB], Z[RPB];
#pragma unroll
    for (int r = 0; r < RPB; ++r) {
        hj[r] = h[(size_t)(j0 + r) * FF + f] * LOG2E;   // fold log2e
        Z[r] = 0.f;
    }
    const float* hp = h + (size_t)(i0 + team * TLEN) * FF + f;
    const float* sp = sl + team * TLEN * RPB;
#pragma unroll 2
    for (int ii = 0; ii < TLEN; ++ii) {
        const float hif = hp[(size_t)ii * FF];          // 1 load serves 8 rows
        const f4 sa = ((const f4*)(sp + ii * RPB))[0];  // b128 broadcast
        const f4 sb = ((const f4*)(sp + ii * RPB))[1];
        const float sv[8] = {sa.x, sa.y, sa.z, sa.w, sb.x, sb.y, sb.z, sb.w};
#pragma unroll
        for (int r = 0; r < RPB; ++r) {
            const float y = sv[r] * hj[r] * hif;
            Z[r] += __builtin_amdgcn_exp2f(fmaxf(y, 0.2f * y));  // lrelu folded
        }
    }
#pragma unroll
    for (int r = 0; r < RPB; ++r) ps[(team * RPB + r) * FF + f] = Z[r];
    __syncthreads();
#pragma unroll
    for (int p = 0; p < 2; ++p) {       // 2048 outputs / 1024 threads
        const int idx = tid + p * 1024;
        const int r = idx >> 8, ff = idx & 255;
        const float z = ps[r * FF + ff] + ps[(RPB + r) * FF + ff]
                      + ps[(2 * RPB + r) * FF + ff] + ps[(3 * RPB + r) * FF + ff];
        Zp[((size_t)blockIdx.y * EE + j0 + r) * FF + ff] = z;
    }
}

// --- kBe: hg[j,f] = {h, h * rcp(sum_c Zp[c][j,f])} -------------------------
__global__ __launch_bounds__(256) void kBe(const float* __restrict__ h,
                                           const float* __restrict__ Zp,
                                           f2* __restrict__ hg) {
    const int j = blockIdx.x, f = threadIdx.x;
    const size_t o = (size_t)j * FF + f;
    const float Zt = Zp[o] + Zp[(size_t)EE * FF + o]
                   + Zp[2 * (size_t)EE * FF + o] + Zp[3 * (size_t)EE * FF + o];
    const float hv = h[o];
    hg[o] = (f2){hv, hv * __builtin_amdgcn_rcpf(Zt)};
}

// --- kC: Hp[c][i,f] = sum_{j in chunk c} g*exp2(lrelu(s*h_if*h_jf)*log2e) --
__global__ __launch_bounds__(1024, 2) void kC(const float* __restrict__ h,
                                              const float* __restrict__ s,
                                              const f2* __restrict__ hg,
                                              float* __restrict__ Hp) {
    const int tid  = threadIdx.x;
    const int f    = tid & 255;
    const int team = tid >> 8;
    const int i0   = blockIdx.x * RPB;
    const int j0   = blockIdx.y * CH;
    __shared__ __align__(16) float sl[CH * RPB];   // [jj][ri]
    __shared__ float ps[4 * RPB * FF];
    sl[tid] = s[(size_t)(i0 + (tid & 7)) * EE + j0 + (tid >> 3)];
    __syncthreads();
    float hl[RPB], acc[RPB];
#pragma unroll
    for (int r = 0; r < RPB; ++r) {
        hl[r] = h[(size_t)(i0 + r) * FF + f] * LOG2E;
        acc[r] = 0.f;
    }
    const f2* hgp = hg + (size_t)(j0 + team * TLEN) * FF + f;
    const float* sp = sl + team * TLEN * RPB;
#pragma unroll 2
    for (int jj = 0; jj < TLEN; ++jj) {
        const f2 hgv = hgp[(size_t)jj * FF];            // {h_jf, g_jf}: serves 8 rows
        const f4 sa = ((const f4*)(sp + jj * RPB))[0];  // b128 broadcast
        const f4 sb = ((const f4*)(sp + jj * RPB))[1];
        const float sv[8] = {sa.x, sa.y, sa.z, sa.w, sb.x, sb.y, sb.z, sb.w};
#pragma unroll
        for (int r = 0; r < RPB; ++r) {
            const float y = sv[r] * hl[r] * hgv.x;
            acc[r] = fmaf(__builtin_amdgcn_exp2f(fmaxf(y, 0.2f * y)), hgv.y, acc[r]);
        }
    }
#pragma unroll
    for (int r = 0; r < RPB; ++r) ps[(team * RPB + r) * FF + f] = acc[r];
    __syncthreads();
#pragma unroll
    for (int p = 0; p < 2; ++p) {
        const int idx = tid + p * 1024;
        const int r = idx >> 8, ff = idx & 255;
        const float a = ps[r * FF + ff] + ps[(RPB + r) * FF + ff]
                      + ps[(2 * RPB + r) * FF + ff] + ps[(3 * RPB + r) * FF + ff];
        Hp[((size_t)blockIdx.y * EE + i0 + r) * FF + ff] = a;
    }
}

// --- kCe: out[i,f] = elu(sum_c Hp[c][i,f]) ---------------------------------
__global__ __launch_bounds__(256) void kCe(const float* __restrict__ Hp,
                                           float* __restrict__ out) {
    const int i = blockIdx.x, f = threadIdx.x;
    const size_t o = (size_t)i * FF + f;
    const float a = Hp[o] + Hp[(size_t)EE * FF + o]
                  + Hp[2 * (size_t)EE * FF + o] + Hp[3 * (size_t)EE * FF + o];
    out[o] = (a > 0.f) ? a : (__expf(a) - 1.0f);
}

extern "C" void kernel_launch(void* const* d_in, const int* in_sizes, int n_in,
                              void* d_out, int out_size, void* d_ws, size_t ws_size,
                              hipStream_t stream) {
    const float* h   = (const float*)d_in[0];  // [E,F]
    const float* adj = (const float*)d_in[1];  // [R,E,E]
    // lin_w / lin_b mathematically dead (alpha uniform).

    float* s   = (float*)d_ws;                      // 1 MB
    f2*    hg  = (f2*)(s + (size_t)EE * EE);        // 1 MB
    float* Zp  = (float*)(hg + (size_t)EE * FF);    // 2 MB (SCH partials)
    float* Hp  = Zp + (size_t)SCH * EE * FF;        // 2 MB (total 6 MB)
    float* out = (float*)d_out;

    kA <<<EE, 256, 0, stream>>>(adj, s, out);
    kB <<<dim3(EE / RPB, SCH), 1024, 0, stream>>>(h, s, Zp);
    kBe<<<EE, 256, 0, stream>>>(h, Zp, hg);
    kC <<<dim3(EE / RPB, SCH), 1024, 0, stream>>>(h, s, hg, Hp);
    kCe<<<EE, 256, 0, stream>>>(Hp, out);
}

// Round 13
// 37.417 us; speedup vs baseline: 1.5293x; 1.1859x over previous
//
#include <hip/hip_runtime.h>

// CenterNeighAtt on MI355X. E=512, F=256, R=4.
//
// Exact math simplifications (validated R1-R12, absmax ~5e-4 vs 2.3e-3 threshold):
//  * alpha = softmax_j(sum_i scores[i,j]) is uniform 1/E: sum_i attention[i,j,f]==1,
//    so column sums of scores are constant in j. lin_w/lin_b are dead inputs.
//  * No max-subtraction in softmaxes: logits bounded (~20), exp far below f32 overflow.
//
// Structure lessons (measured):
//  * Cross-grid sync / __threadfence in-dispatch: toxic (R3/R5/R6/R7). Kernel
//    boundaries + plain stores ONLY. Per-dispatch gap ~3us.
//  * Interiors mixed issue/L2-bound: traffic = E^2*F*B/rpb (R11/R12 A/B).
//    R12's rpb=8 interiors were ~5us faster; 2 extra dispatches ate the win.
//  * Rule #20: only tiny fully-unrolled per-thread arrays. No VOP3P asm (R10).
//
// R13: 3 dispatches, full-K in-block reduction at rpb=4 via f-split blocks.
//  kB/kC: grid (128 row-groups x 4 f-quarters) x 1024 thr = 512 blocks = 2 blk/CU
//  = 8 waves/SIMD (launch_bounds(1024,8) caps VGPR<=64; loop needs ~30).
//  16 teams x 32-length chunks cover K=512 in-block; ps-reduce in LDS; 1 global
//  h/hg load serves 4 rows.

typedef float f2 __attribute__((ext_vector_type(2)));
typedef float f4 __attribute__((ext_vector_type(4)));

#define EE 512
#define FF 256
#define RRR 4
#define LOG2E 1.44269504088896340736f
#define RPB 4      // rows per block
#define NT 16      // teams (chunk = 512/16 = 32)
#define CHL 32     // chunk length
#define FB 64      // f per block

// --- kA: s[i,:] = softmax_j(sum_r adj[r,i,:]); alpha -----------------------
__global__ __launch_bounds__(256) void kA(const float* __restrict__ adj,
                                          float* __restrict__ s,
                                          float* __restrict__ out) {
    const int i = blockIdx.x;
    const int t = threadIdx.x;
    if (i == 0) {   // alpha: softmax of a constant vector = uniform 1/E
        out[EE * FF + t]       = 1.0f / EE;
        out[EE * FF + 256 + t] = 1.0f / EE;
    }
    const float* base = adj + (size_t)i * EE;
    float t0 = 0.f, t1 = 0.f;
#pragma unroll
    for (int r = 0; r < RRR; ++r) {
        t0 += base[(size_t)r * EE * EE + t];
        t1 += base[(size_t)r * EE * EE + t + 256];
    }
    const float e0 = __expf(t0);
    const float e1 = __expf(t1);
    __shared__ float red[256];
    red[t] = e0 + e1;
    __syncthreads();
    for (int off = 128; off > 0; off >>= 1) {
        if (t < off) red[t] += red[t + off];
        __syncthreads();
    }
    const float inv = 1.0f / red[0];
    s[(size_t)i * EE + t]       = e0 * inv;
    s[(size_t)i * EE + t + 256] = e1 * inv;
}

// --- kB: Z[j,f] = sum_i exp2(lrelu(s[i,j]*h[i,f]*h[j,f])*log2e);
//         hg[j,f] = {h[j,f], h[j,f]*rcp(Z)} --------------------------------
__global__ __launch_bounds__(1024, 8) void kB(const float* __restrict__ h,
                                              const float* __restrict__ s,
                                              f2* __restrict__ hg) {
    const int tid  = threadIdx.x;
    const int fl   = tid & (FB - 1);        // 0..63
    const int team = tid >> 6;              // 0..15
    const int j0   = blockIdx.x * RPB;      // 128 row-groups
    const int f    = blockIdx.y * FB + fl;  // f-quarter
    __shared__ __align__(16) float sl[EE * RPB];  // sl[i*4+r] = s[i][j0+r]  (8 KB)
    __shared__ float ps[NT * RPB * FB];           // 16 KB
#pragma unroll
    for (int p = 0; p < 2; ++p) {           // stage 2048 floats
        const int idx = tid + p * 1024;
        sl[idx] = s[(size_t)(idx >> 2) * EE + j0 + (idx & 3)];
    }
    __syncthreads();
    float hj0 = h[(size_t)j0 * FF + f] * LOG2E;   // fold log2e
    float hj1 = h[(size_t)(j0 + 1) * FF + f] * LOG2E;
    float hj2 = h[(size_t)(j0 + 2) * FF + f] * LOG2E;
    float hj3 = h[(size_t)(j0 + 3) * FF + f] * LOG2E;
    float Z0 = 0.f, Z1 = 0.f, Z2 = 0.f, Z3 = 0.f;
    const float* hp = h + (size_t)(team * CHL) * FF + f;
    const f4* spv = (const f4*)(sl + team * CHL * RPB);
#pragma unroll 4
    for (int ii = 0; ii < CHL; ++ii) {
        const float hif = hp[(size_t)ii * FF];    // 1 load serves 4 rows
        const f4 sv = spv[ii];                    // ds_read_b128 broadcast
        const float y0 = sv.x * hj0 * hif;
        const float y1 = sv.y * hj1 * hif;
        const float y2 = sv.z * hj2 * hif;
        const float y3 = sv.w * hj3 * hif;
        Z0 += __builtin_amdgcn_exp2f(fmaxf(y0, 0.2f * y0));   // lrelu folded
        Z1 += __builtin_amdgcn_exp2f(fmaxf(y1, 0.2f * y1));
        Z2 += __builtin_amdgcn_exp2f(fmaxf(y2, 0.2f * y2));
        Z3 += __builtin_amdgcn_exp2f(fmaxf(y3, 0.2f * y3));
    }
    ps[(team * RPB + 0) * FB + fl] = Z0;
    ps[(team * RPB + 1) * FB + fl] = Z1;
    ps[(team * RPB + 2) * FB + fl] = Z2;
    ps[(team * RPB + 3) * FB + fl] = Z3;
    __syncthreads();
    if (tid < RPB * FB) {                    // 256 outputs: r = tid>>6, fl2 = tid&63
        const int r = tid >> 6, fl2 = tid & (FB - 1);
        float Zt = 0.f;
#pragma unroll
        for (int t = 0; t < NT; ++t) Zt += ps[(t * RPB + r) * FB + fl2];
        const size_t o = (size_t)(j0 + r) * FF + blockIdx.y * FB + fl2;
        const float hv = h[o];
        hg[o] = (f2){hv, hv * __builtin_amdgcn_rcpf(Zt)};
    }
}

// --- kC: out[i,f] = elu(sum_j g[j,f]*exp2(lrelu(s[i,j]*h[i,f]*h[j,f])*log2e))
__global__ __launch_bounds__(1024, 8) void kC(const float* __restrict__ h,
                                              const float* __restrict__ s,
                                              const f2* __restrict__ hg,
                                              float* __restrict__ out) {
    const int tid  = threadIdx.x;
    const int fl   = tid & (FB - 1);
    const int team = tid >> 6;
    const int i0   = blockIdx.x * RPB;
    const int f    = blockIdx.y * FB + fl;
    __shared__ __align__(16) float sl[EE * RPB];  // sl[j*4+r] = s[i0+r][j]
    __shared__ float ps[NT * RPB * FB];
#pragma unroll
    for (int p = 0; p < 2; ++p) {
        const int idx = tid + p * 1024;
        sl[idx] = s[(size_t)(i0 + (idx & 3)) * EE + (idx >> 2)];
    }
    __syncthreads();
    float hl0 = h[(size_t)i0 * FF + f] * LOG2E;
    float hl1 = h[(size_t)(i0 + 1) * FF + f] * LOG2E;
    float hl2 = h[(size_t)(i0 + 2) * FF + f] * LOG2E;
    float hl3 = h[(size_t)(i0 + 3) * FF + f] * LOG2E;
    float a0 = 0.f, a1 = 0.f, a2 = 0.f, a3 = 0.f;
    const f2* hgp = hg + (size_t)(team * CHL) * FF + f;
    const f4* spv = (const f4*)(sl + team * CHL * RPB);
#pragma unroll 4
    for (int jj = 0; jj < CHL; ++jj) {
        const f2 hgv = hgp[(size_t)jj * FF];      // {h_jf, g_jf}: serves 4 rows
        const f4 sv = spv[jj];                    // ds_read_b128 broadcast
        const float y0 = sv.x * hl0 * hgv.x;
        const float y1 = sv.y * hl1 * hgv.x;
        const float y2 = sv.z * hl2 * hgv.x;
        const float y3 = sv.w * hl3 * hgv.x;
        a0 = fmaf(__builtin_amdgcn_exp2f(fmaxf(y0, 0.2f * y0)), hgv.y, a0);
        a1 = fmaf(__builtin_amdgcn_exp2f(fmaxf(y1, 0.2f * y1)), hgv.y, a1);
        a2 = fmaf(__builtin_amdgcn_exp2f(fmaxf(y2, 0.2f * y2)), hgv.y, a2);
        a3 = fmaf(__builtin_amdgcn_exp2f(fmaxf(y3, 0.2f * y3)), hgv.y, a3);
    }
    ps[(team * RPB + 0) * FB + fl] = a0;
    ps[(team * RPB + 1) * FB + fl] = a1;
    ps[(team * RPB + 2) * FB + fl] = a2;
    ps[(team * RPB + 3) * FB + fl] = a3;
    __syncthreads();
    if (tid < RPB * FB) {
        const int r = tid >> 6, fl2 = tid & (FB - 1);
        float a = 0.f;
#pragma unroll
        for (int t = 0; t < NT; ++t) a += ps[(t * RPB + r) * FB + fl2];
        out[(size_t)(i0 + r) * FF + blockIdx.y * FB + fl2] =
            (a > 0.f) ? a : (__expf(a) - 1.0f);
    }
}

extern "C" void kernel_launch(void* const* d_in, const int* in_sizes, int n_in,
                              void* d_out, int out_size, void* d_ws, size_t ws_size,
                              hipStream_t stream) {
    const float* h   = (const float*)d_in[0];  // [E,F]
    const float* adj = (const float*)d_in[1];  // [R,E,E]
    // lin_w / lin_b mathematically dead (alpha uniform).

    float* s   = (float*)d_ws;                 // 1 MB
    f2*    hg  = (f2*)(s + (size_t)EE * EE);   // 1 MB (total 2 MB)
    float* out = (float*)d_out;

    kA<<<EE, 256, 0, stream>>>(adj, s, out);
    kB<<<dim3(EE / RPB, FF / FB), 1024, 0, stream>>>(h, s, hg);
    kC<<<dim3(EE / RPB, FF / FB), 1024, 0, stream>>>(h, s, hg, out);
}